// Round 6
// baseline (389.138 us; speedup 1.0000x reference)
//
#include <hip/hip_runtime.h>
#include <cmath>

// B=8, C=64, H=256, W=256, k=3, pad=1 (H only)
#define HW 65536
#define NPER 524288   // B*H*W per channel for BN
#define NBLK 8192     // dcn_fused grid (one block = 64 pixels)

typedef _Float16 f16;
typedef __attribute__((ext_vector_type(8))) _Float16 f16x8;
typedef __attribute__((ext_vector_type(4))) _Float16 f16x4;
typedef __attribute__((ext_vector_type(4))) float f32x4;

__device__ __forceinline__ f16x8 splat8(f16 h) {
  f16x8 r = {h, h, h, h, h, h, h, h};
  return r;
}

// ws layout (floats):
//  part32 @0       : 32*128 BN partials (atomicAdd targets, zeroed each launch)
//  wtO   @4096     : 3072 halves  [16 n][192 k] fp16 (n>=9 zeroed)
//  wtH   @5632     : 12288 halves [64 o][192 k] fp16
//  xT    @1056384  : 8 b * 65536 px * 64 ch halves (67 MB)
//  out16 @17833600 : 8 b * 64 o * 65536 px halves (67 MB, pre-BN)
#define PART32_OFF 0
#define WTO_OFF   4096
#define WTH_OFF   5632
#define XT_OFF    1056384
#define OUT16_OFF 17833600

__global__ __launch_bounds__(256) void prep_wts(
    const float* __restrict__ w_off, const float* __restrict__ w_dcn,
    f16* __restrict__ wtO, f16* __restrict__ wtH, float* __restrict__ part32) {
  int i = blockIdx.x * 256 + threadIdx.x;
  if (i < 4096) part32[i] = 0.f;   // zeroed for dcn_fused atomics
  if (i < 12288) {
    int o = i / 192, k = i - o * 192, kh = k >> 6, c = k & 63;
    wtH[i] = (f16)w_dcn[(o * 64 + c) * 3 + kh];
  }
  if (i < 3072) {
    int n = i / 192, k = i - n * 192, kh = k >> 6, c = k & 63;
    wtO[i] = (n < 9) ? (f16)w_off[(n * 64 + c) * 3 + kh] : (f16)0.f;
  }
}

// x[b][c][h][w] fp32 -> xT[b][h*256+w][c] fp16 (all 8 batches).
// float4 loads (16B/lane), LDS transpose, dense 32B/lane global writes.
__global__ __launch_bounds__(256) void xpose(
    const float* __restrict__ x, f16* __restrict__ xT) {
  __shared__ f16 sX[64 * 68];   // [px][68] pad: ~2-way banks (free)
  int t = threadIdx.x;
  int blk = blockIdx.x;
  int b = blk >> 10;
  int rem = blk & 1023;
  int h = rem >> 2, w0 = (rem & 3) << 6;
  int c = t >> 2, w4 = t & 3;                   // c 0..63, w4 0..3
  const float* xb = x + (((size_t)b << 6) + c) * HW + (size_t)h * 256 + w0;
  float4 v[4];
#pragma unroll
  for (int i = 0; i < 4; ++i)
    v[i] = *(const float4*)(xb + ((w4 + 4 * i) << 2));
#pragma unroll
  for (int i = 0; i < 4; ++i) {
    int w = (w4 + 4 * i) << 2;
    sX[(w + 0) * 68 + c] = (f16)v[i].x;
    sX[(w + 1) * 68 + c] = (f16)v[i].y;
    sX[(w + 2) * 68 + c] = (f16)v[i].z;
    sX[(w + 3) * 68 + c] = (f16)v[i].w;
  }
  __syncthreads();
  int px = t >> 2, c16 = (t & 3) << 4;          // byte off = t*32: dense
  f16x8 o0 = *(const f16x8*)(sX + px * 68 + c16);
  f16x8 o1 = *(const f16x8*)(sX + px * 68 + c16 + 8);
  f16* dst = xT + (((size_t)b * HW + (size_t)h * 256 + w0 + px) << 6) + c16;
  *(f16x8*)dst = o0;
  *(f16x8*)(dst + 8) = o1;
}

// Fused per 64-pixel tile (one b,h, 64 w). WAVE-LOCAL front half (R4):
// wave cq owns tile pixels [c0, c0+16). A (offset conv), W (interp params),
// B (gather+FMA -> sA) are per-wave, no block barriers; 2 barriers total.
// R5: out16 stores are NON-TEMPORAL (nt: no L2 allocate) — the write
// stream was suspected of evicting the xT gather working set from the 4MB
// per-XCD L2 (all pipes idle + occupancy-insensitive = cache-side latency).
// BN partials: each wave owns 16 disjoint channels -> 32 fire-and-forget
// atomicAdds into part32[blk&31][128]; reduce_sums kernel deleted.
__global__ __launch_bounds__(256, 5) void dcn_fused(
    const f16* __restrict__ xT, const f16* __restrict__ wtO,
    const float* __restrict__ b_off, const f16* __restrict__ wtH,
    const float* __restrict__ b_dcn, f16* __restrict__ out16,
    float* __restrict__ part32) {
  __shared__ __align__(16) unsigned char lds[25600];
  f16*   sA   = (f16*)lds;                 // [64 px][200] f16 (row = px*400B), B->C
  float* sOut = (float*)lds;               // [64 o][66] f32 (alias), D->E

  const int t = threadIdx.x, lane = t & 63, cq = t >> 6;
  const int c0 = cq << 4;
  const int lrow = lane & 15, lq = lane >> 4, kgrp = lq << 3;
  const int pix8 = lane >> 3, chunk = lane & 7;        // phase-B mapping
  const int cb8 = chunk << 3;

  // Per-wave scratch inside own sA quarter (bytes [cq*6400, cq*6400+1920)).
  unsigned char* wq = lds + cq * 6400;
  float* sOMw = (float*)wq;                             // [16 px][17] f32, A->W
  unsigned short* sWoW = (unsigned short*)(wq + 1152);  // [48][4] r0,r1,c0,c1, W->B
  f16*   sWwW = (f16*)(wq + 1536);                      // [48][4] w00..w11, W->B

  // XCD swizzle: XCD (blk&7) owns batch b = blk&7's image (L2 locality)
  int g = ((blockIdx.x & 7) << 10) | (blockIdx.x >> 3);
  int b = g >> 10;
  int rem = g & 1023;
  int h = rem >> 2, w0 = (rem & 3) << 6;
  const f16* xb = xT + (((size_t)b * HW) << 6);

  // ---- Phase A: offset conv. A-frag rows = pixels c0..c0+15, direct load ----
  f16x8 Ac[6];
#pragma unroll
  for (int kt = 0; kt < 6; ++kt) {
    int hr = h + (kt >> 1) - 1;                 // x row for this k-chunk
    int hc = min(max(hr, 0), 255);
    int cb = ((kt & 1) << 5) + kgrp;
    const f16* src = xb + (((size_t)(hc * 256 + w0 + c0 + lrow)) << 6) + cb;
    f16x8 v = *(const f16x8*)src;
    if (!(hr >= 0 && hr < 256)) v = splat8((f16)0.f);  // wave-uniform pad
    Ac[kt] = v;
  }
  f32x4 accO = {0.f, 0.f, 0.f, 0.f};
#pragma unroll
  for (int kt = 0; kt < 6; ++kt) {
    f16x8 Bo = *(const f16x8*)(wtO + lrow * 192 + kt * 32 + kgrp);
    accO = __builtin_amdgcn_mfma_f32_16x16x32_f16(Ac[kt], Bo, accO, 0, 0, 0);
  }
  float boffv = (lrow < 9) ? b_off[lrow] : 0.f;
#pragma unroll
  for (int r = 0; r < 4; ++r)
    sOMw[(lq * 4 + r) * 17 + lrow] = accO[r] + boffv;   // own pixels only

  // ---- Phase W (wave-local): lane = lp*4+kh, kh<3 active ----
  {
    int lp = lane >> 2, kh3 = lane & 3;
    if (kh3 < 3) {
      float dy   = sOMw[lp * 17 + kh3];
      float dxv  = sOMw[lp * 17 + 3 + kh3];
      float mpre = sOMw[lp * 17 + 6 + kh3];
      float m = 1.f / (1.f + __expf(-mpre));
      float yf = (float)(h + kh3) + dy;           // xp coords
      float xf = (float)(w0 + c0 + lp) + dxv;     // pixel = c0+lp
      float y0f = floorf(yf), x0f = floorf(xf);
      int iy0 = (int)y0f, ix0 = (int)x0f;
      float wy1 = yf - y0f, wy0 = 1.f - wy1;
      float wx1 = xf - x0f, wx0 = 1.f - wx1;
      int r0 = iy0 - 1, r1 = iy0, g0 = ix0, g1 = ix0 + 1;  // x rows/cols
      bool vr0 = (r0 >= 0) & (r0 < 256), vr1 = (r1 >= 0) & (r1 < 256);
      bool vc0 = (g0 >= 0) & (g0 < 256), vc1 = (g1 >= 0) & (g1 < 256);
      float w00 = (vr0 & vc0) ? wy0 * wx0 * m : 0.f;
      float w01 = (vr0 & vc1) ? wy0 * wx1 * m : 0.f;
      float w10 = (vr1 & vc0) ? wy1 * wx0 * m : 0.f;
      float w11 = (vr1 & vc1) ? wy1 * wx1 * m : 0.f;
      int e = lp * 3 + kh3;
      sWoW[e * 4 + 0] = (unsigned short)min(max(r0, 0), 255);
      sWoW[e * 4 + 1] = (unsigned short)min(max(r1, 0), 255);
      sWoW[e * 4 + 2] = (unsigned short)min(max(g0, 0), 255);
      sWoW[e * 4 + 3] = (unsigned short)min(max(g1, 0), 255);
      sWwW[e * 4 + 0] = (f16)w00;
      sWwW[e * 4 + 1] = (f16)w01;
      sWwW[e * 4 + 2] = (f16)w10;
      sWwW[e * 4 + 3] = (f16)w11;
    }
  }

  // ---- Phase B (wave-local): params -> regs, 24 gathers, FMA -> sA ----
  ushort4 po[6];
  f16x4  wv[6];
#pragma unroll
  for (int i = 0; i < 6; ++i) {
    int kh = i >> 1, half = i & 1;
    int e = (half * 8 + pix8) * 3 + kh;           // local pixel index
    po[i] = *(const ushort4*)(sWoW + e * 4);
    wv[i] = *(const f16x4*)(sWwW + e * 4);
  }
  f16x8 gv[24];
#pragma unroll
  for (int i = 0; i < 6; ++i) {
    int b00 = (((int)po[i].x << 8) + (int)po[i].z) << 6;
    int b01 = (((int)po[i].x << 8) + (int)po[i].w) << 6;
    int b10 = (((int)po[i].y << 8) + (int)po[i].z) << 6;
    int b11 = (((int)po[i].y << 8) + (int)po[i].w) << 6;
    gv[i * 4 + 0] = *(const f16x8*)(xb + b00 + cb8);
    gv[i * 4 + 1] = *(const f16x8*)(xb + b01 + cb8);
    gv[i * 4 + 2] = *(const f16x8*)(xb + b10 + cb8);
    gv[i * 4 + 3] = *(const f16x8*)(xb + b11 + cb8);
  }
  // B-fragments (wave's 16 output channels) + bias (global, independent)
  const int nrow = c0 + lrow;                   // output channel o
  f16x8 Bf[6];
#pragma unroll
  for (int kt = 0; kt < 6; ++kt)
    Bf[kt] = *(const f16x8*)(wtH + nrow * 192 + kt * 32 + kgrp);
  float bdc = b_dcn[nrow];

#pragma unroll
  for (int i = 0; i < 6; ++i) {
    int kh = i >> 1, half = i & 1;
    f16x8 s = gv[i * 4 + 0] * splat8(wv[i][0]) +
              gv[i * 4 + 1] * splat8(wv[i][1]) +
              gv[i * 4 + 2] * splat8(wv[i][2]) +
              gv[i * 4 + 3] * splat8(wv[i][3]);
    // own pixels: (c0 + half*8 + pix8) in [c0, c0+16) -> own sA quarter
    *(f16x8*)(sA + (c0 + half * 8 + pix8) * 200 + kh * 64 + cb8) = s;
  }
  __syncthreads();   // barrier #1: all sA written

  // ---- Phase C: MFMA 64x64 += S(64x192) * W(192x64) ----
  f32x4 acc[4];
#pragma unroll
  for (int mt = 0; mt < 4; ++mt) acc[mt] = (f32x4){0.f, 0.f, 0.f, 0.f};
#pragma unroll
  for (int kt = 0; kt < 6; ++kt) {
#pragma unroll
    for (int mt = 0; mt < 4; ++mt) {
      f16x8 Af = *(const f16x8*)(sA + (mt * 16 + lrow) * 200 + kt * 32 + kgrp);
      acc[mt] = __builtin_amdgcn_mfma_f32_16x16x32_f16(Af, Bf[kt], acc[mt],
                                                       0, 0, 0);
    }
  }
  __syncthreads();   // barrier #2: all sA reads done; region becomes sOut

  // ---- Phase D (wave-local rows): +bias, BN partials, sOut[o][66] ----
  float s1 = 0.f, s2 = 0.f;
#pragma unroll
  for (int mt = 0; mt < 4; ++mt) {
    int prow = mt * 16 + lq * 4;                // pixel of acc[mt][0]
    f32x4 vv;
#pragma unroll
    for (int r = 0; r < 4; ++r) {
      float v = acc[mt][r] + bdc;
      vv[r] = v;
      s1 += v;
      s2 += v * v;
    }
    *(f32x4*)(sOut + nrow * 66 + prow) = vv;    // own row (nrow = c0+lrow)
  }
  s1 += __shfl_xor(s1, 16); s1 += __shfl_xor(s1, 32);
  s2 += __shfl_xor(s2, 16); s2 += __shfl_xor(s2, 32);
  // every lane now holds this wave's 64-px totals for ch = c0+(lane&15);
  // waves own disjoint channel sets -> no block combine needed.
  if (lane < 32) {
    int ch = c0 + (lane & 15);
    int j = (lane < 16) ? ch : (64 + ch);
    float v = (lane < 16) ? s1 : s2;
    atomicAdd(&part32[((blockIdx.x & 31) << 7) + j], v);  // fire-and-forget
  }

  // ---- Phase E (wave-local rows, no barrier): NT pre-BN fp16 store ----
  f16* ob = out16 + (((size_t)b) << 6) * HW + (size_t)h * 256 + w0;
#pragma unroll
  for (int i = 0; i < 16; ++i) {
    int o = c0 + i;                             // own rows only
    __builtin_nontemporal_store((f16)sOut[o * 66 + lane],
                                ob + (size_t)o * HW + lane);
  }
}

// out = relu((out16-mean)*rsqrt(var+eps)*gamma + beta)  (fp16 in, fp32 out)
// Preamble folds the 32 BN partials per channel (wave-uniform -> s_loads).
__global__ __launch_bounds__(256) void bn_apply(
    const f16* __restrict__ out16, float* __restrict__ out,
    const float* __restrict__ part32, const float* __restrict__ gamma,
    const float* __restrict__ beta) {
  int blk = blockIdx.x;            // 2048 = 512 planes x 4 quarters
  int pl = blk >> 2, q = blk & 3;
  int o = pl & 63;
  float s1 = 0.f, s2 = 0.f;
#pragma unroll
  for (int s = 0; s < 32; ++s) {
    s1 += part32[(s << 7) + o];
    s2 += part32[(s << 7) + 64 + o];
  }
  float mean = s1 * (1.f / (float)NPER);
  float var = s2 * (1.f / (float)NPER) - mean * mean;
  float inv = rsqrtf(var + 1e-5f);
  float sc = gamma[o] * inv;
  float sh = beta[o] - mean * sc;
  const f16x8* src = (const f16x8*)(out16 + (size_t)pl * HW + q * 16384);
  f32x4* dst = (f32x4*)(out + (size_t)pl * HW + q * 16384);
  for (int i = threadIdx.x; i < 2048; i += 256) {
    f16x8 v = src[i];
    f32x4 lo, hi;
    lo[0] = fmaxf(fmaf((float)v[0], sc, sh), 0.f);
    lo[1] = fmaxf(fmaf((float)v[1], sc, sh), 0.f);
    lo[2] = fmaxf(fmaf((float)v[2], sc, sh), 0.f);
    lo[3] = fmaxf(fmaf((float)v[3], sc, sh), 0.f);
    hi[0] = fmaxf(fmaf((float)v[4], sc, sh), 0.f);
    hi[1] = fmaxf(fmaf((float)v[5], sc, sh), 0.f);
    hi[2] = fmaxf(fmaf((float)v[6], sc, sh), 0.f);
    hi[3] = fmaxf(fmaf((float)v[7], sc, sh), 0.f);
    __builtin_nontemporal_store(lo, dst + 2 * i);       // never re-read
    __builtin_nontemporal_store(hi, dst + 2 * i + 1);
  }
}

extern "C" void kernel_launch(void* const* d_in, const int* in_sizes, int n_in,
                              void* d_out, int out_size, void* d_ws, size_t ws_size,
                              hipStream_t stream) {
  const float* x     = (const float*)d_in[0];
  const float* w_off = (const float*)d_in[1];
  const float* b_off = (const float*)d_in[2];
  const float* w_dcn = (const float*)d_in[3];
  const float* b_dcn = (const float*)d_in[4];
  const float* gamma = (const float*)d_in[5];
  const float* beta  = (const float*)d_in[6];
  float* out = (float*)d_out;
  float* ws  = (float*)d_ws;

  float* part32 = ws + PART32_OFF;
  f16*   wtO  = (f16*)(ws + WTO_OFF);
  f16*   wtH  = (f16*)(ws + WTH_OFF);
  f16*   xT   = (f16*)(ws + XT_OFF);
  f16*   o16  = (f16*)(ws + OUT16_OFF);

  prep_wts<<<48, 256, 0, stream>>>(w_off, w_dcn, wtO, wtH, part32);
  xpose<<<8192, 256, 0, stream>>>(x, xT);
  dcn_fused<<<NBLK, 256, 0, stream>>>(xT, wtO, b_off, wtH, b_dcn, o16, part32);
  bn_apply<<<2048, 256, 0, stream>>>(o16, out, part32, gamma, beta);
}

// Round 7
// 368.349 us; speedup vs baseline: 1.0564x; 1.0564x over previous
//
#include <hip/hip_runtime.h>
#include <cmath>

// B=8, C=64, H=256, W=256, k=3, pad=1 (H only)
#define HW 65536
#define NPER 524288   // B*H*W per channel for BN
#define NBLK 8192     // dcn_fused grid (one block = 64 pixels)

typedef _Float16 f16;
typedef __attribute__((ext_vector_type(8))) _Float16 f16x8;
typedef __attribute__((ext_vector_type(4))) _Float16 f16x4;
typedef __attribute__((ext_vector_type(4))) float f32x4;

__device__ __forceinline__ f16x8 splat8(f16 h) {
  f16x8 r = {h, h, h, h, h, h, h, h};
  return r;
}

// ws layout (floats):
//  part32 @0       : 32*128 BN partials (atomicAdd targets, zeroed each launch)
//  wtO   @4096     : 3072 halves  [16 n][192 k] fp16 (n>=9 zeroed)
//  wtH   @5632     : 12288 halves [64 o][192 k] fp16
//  xT    @1056384  : 8 b * 65536 px * 64 ch halves (67 MB)
//  out16 @17833600 : 8 b * 64 o * 65536 px halves (67 MB, pre-BN)
#define PART32_OFF 0
#define WTO_OFF   4096
#define WTH_OFF   5632
#define XT_OFF    1056384
#define OUT16_OFF 17833600

__global__ __launch_bounds__(256) void prep_wts(
    const float* __restrict__ w_off, const float* __restrict__ w_dcn,
    f16* __restrict__ wtO, f16* __restrict__ wtH, float* __restrict__ part32) {
  int i = blockIdx.x * 256 + threadIdx.x;
  if (i < 4096) part32[i] = 0.f;   // zeroed for dcn_fused atomics
  if (i < 12288) {
    int o = i / 192, k = i - o * 192, kh = k >> 6, c = k & 63;
    wtH[i] = (f16)w_dcn[(o * 64 + c) * 3 + kh];
  }
  if (i < 3072) {
    int n = i / 192, k = i - n * 192, kh = k >> 6, c = k & 63;
    wtO[i] = (n < 9) ? (f16)w_off[(n * 64 + c) * 3 + kh] : (f16)0.f;
  }
}

// x[b][c][h][w] fp32 -> xT[b][h*256+w][c] fp16 (all 8 batches).
// float4 loads (16B/lane), LDS transpose, dense 32B/lane global writes.
__global__ __launch_bounds__(256) void xpose(
    const float* __restrict__ x, f16* __restrict__ xT) {
  __shared__ f16 sX[64 * 68];   // [px][68] pad: ~2-way banks (free)
  int t = threadIdx.x;
  int blk = blockIdx.x;
  int b = blk >> 10;
  int rem = blk & 1023;
  int h = rem >> 2, w0 = (rem & 3) << 6;
  int c = t >> 2, w4 = t & 3;                   // c 0..63, w4 0..3
  const float* xb = x + (((size_t)b << 6) + c) * HW + (size_t)h * 256 + w0;
  float4 v[4];
#pragma unroll
  for (int i = 0; i < 4; ++i)
    v[i] = *(const float4*)(xb + ((w4 + 4 * i) << 2));
#pragma unroll
  for (int i = 0; i < 4; ++i) {
    int w = (w4 + 4 * i) << 2;
    sX[(w + 0) * 68 + c] = (f16)v[i].x;
    sX[(w + 1) * 68 + c] = (f16)v[i].y;
    sX[(w + 2) * 68 + c] = (f16)v[i].z;
    sX[(w + 3) * 68 + c] = (f16)v[i].w;
  }
  __syncthreads();
  int px = t >> 2, c16 = (t & 3) << 4;          // byte off = t*32: dense
  f16x8 o0 = *(const f16x8*)(sX + px * 68 + c16);
  f16x8 o1 = *(const f16x8*)(sX + px * 68 + c16 + 8);
  f16* dst = xT + (((size_t)b * HW + (size_t)h * 256 + w0 + px) << 6) + c16;
  *(f16x8*)dst = o0;
  *(f16x8*)(dst + 8) = o1;
}

// Fused per 64-pixel tile (one b,h, 64 w). WAVE-LOCAL front half (R4):
// wave cq owns tile pixels [c0, c0+16). A (offset conv), W (interp params),
// B (gather+FMA -> sA) are per-wave, no block barriers; 2 barriers total.
// R7: __launch_bounds__(256,3) — VGPR cap ~168 so the FULL 24-gather window
// (gv = 96 VGPR) stays register-resident in ONE vmcnt window. At VGPR=44 the
// compiler strip-mined phase B into ~6 serialized load->wait->FMA rounds
// (~500cy each) — the latency elephant all prior structural fixes missed.
// Bf/bdc loads moved AFTER the interp FMA to shrink the live set.
// Occupancy drops to 3 blocks/CU — R3 proved occupancy isn't binding here.
// BN partials: each wave owns 16 disjoint channels -> 32 fire-and-forget
// atomicAdds into part32[blk&31][128]; no reduce kernel.
__global__ __launch_bounds__(256, 3) void dcn_fused(
    const f16* __restrict__ xT, const f16* __restrict__ wtO,
    const float* __restrict__ b_off, const f16* __restrict__ wtH,
    const float* __restrict__ b_dcn, f16* __restrict__ out16,
    float* __restrict__ part32) {
  __shared__ __align__(16) unsigned char lds[25600];
  f16*   sA   = (f16*)lds;                 // [64 px][200] f16 (row = px*400B), B->C
  float* sOut = (float*)lds;               // [64 o][66] f32 (alias), D->E

  const int t = threadIdx.x, lane = t & 63, cq = t >> 6;
  const int c0 = cq << 4;
  const int lrow = lane & 15, lq = lane >> 4, kgrp = lq << 3;
  const int pix8 = lane >> 3, chunk = lane & 7;        // phase-B mapping
  const int cb8 = chunk << 3;

  // Per-wave scratch inside own sA quarter (bytes [cq*6400, cq*6400+1920)).
  unsigned char* wq = lds + cq * 6400;
  float* sOMw = (float*)wq;                             // [16 px][17] f32, A->W
  unsigned short* sWoW = (unsigned short*)(wq + 1152);  // [48][4] r0,r1,c0,c1, W->B
  f16*   sWwW = (f16*)(wq + 1536);                      // [48][4] w00..w11, W->B

  // XCD swizzle: XCD (blk&7) owns batch b = blk&7's image (L2 locality)
  int g = ((blockIdx.x & 7) << 10) | (blockIdx.x >> 3);
  int b = g >> 10;
  int rem = g & 1023;
  int h = rem >> 2, w0 = (rem & 3) << 6;
  const f16* xb = xT + (((size_t)b * HW) << 6);

  // ---- Phase A: offset conv. A-frag rows = pixels c0..c0+15, direct load ----
  f16x8 Ac[6];
#pragma unroll
  for (int kt = 0; kt < 6; ++kt) {
    int hr = h + (kt >> 1) - 1;                 // x row for this k-chunk
    int hc = min(max(hr, 0), 255);
    int cb = ((kt & 1) << 5) + kgrp;
    const f16* src = xb + (((size_t)(hc * 256 + w0 + c0 + lrow)) << 6) + cb;
    f16x8 v = *(const f16x8*)src;
    if (!(hr >= 0 && hr < 256)) v = splat8((f16)0.f);  // wave-uniform pad
    Ac[kt] = v;
  }
  f32x4 accO = {0.f, 0.f, 0.f, 0.f};
#pragma unroll
  for (int kt = 0; kt < 6; ++kt) {
    f16x8 Bo = *(const f16x8*)(wtO + lrow * 192 + kt * 32 + kgrp);
    accO = __builtin_amdgcn_mfma_f32_16x16x32_f16(Ac[kt], Bo, accO, 0, 0, 0);
  }
  float boffv = (lrow < 9) ? b_off[lrow] : 0.f;
#pragma unroll
  for (int r = 0; r < 4; ++r)
    sOMw[(lq * 4 + r) * 17 + lrow] = accO[r] + boffv;   // own pixels only

  // ---- Phase W (wave-local): lane = lp*4+kh, kh<3 active ----
  {
    int lp = lane >> 2, kh3 = lane & 3;
    if (kh3 < 3) {
      float dy   = sOMw[lp * 17 + kh3];
      float dxv  = sOMw[lp * 17 + 3 + kh3];
      float mpre = sOMw[lp * 17 + 6 + kh3];
      float m = 1.f / (1.f + __expf(-mpre));
      float yf = (float)(h + kh3) + dy;           // xp coords
      float xf = (float)(w0 + c0 + lp) + dxv;     // pixel = c0+lp
      float y0f = floorf(yf), x0f = floorf(xf);
      int iy0 = (int)y0f, ix0 = (int)x0f;
      float wy1 = yf - y0f, wy0 = 1.f - wy1;
      float wx1 = xf - x0f, wx0 = 1.f - wx1;
      int r0 = iy0 - 1, r1 = iy0, g0 = ix0, g1 = ix0 + 1;  // x rows/cols
      bool vr0 = (r0 >= 0) & (r0 < 256), vr1 = (r1 >= 0) & (r1 < 256);
      bool vc0 = (g0 >= 0) & (g0 < 256), vc1 = (g1 >= 0) & (g1 < 256);
      float w00 = (vr0 & vc0) ? wy0 * wx0 * m : 0.f;
      float w01 = (vr0 & vc1) ? wy0 * wx1 * m : 0.f;
      float w10 = (vr1 & vc0) ? wy1 * wx0 * m : 0.f;
      float w11 = (vr1 & vc1) ? wy1 * wx1 * m : 0.f;
      int e = lp * 3 + kh3;
      sWoW[e * 4 + 0] = (unsigned short)min(max(r0, 0), 255);
      sWoW[e * 4 + 1] = (unsigned short)min(max(r1, 0), 255);
      sWoW[e * 4 + 2] = (unsigned short)min(max(g0, 0), 255);
      sWoW[e * 4 + 3] = (unsigned short)min(max(g1, 0), 255);
      sWwW[e * 4 + 0] = (f16)w00;
      sWwW[e * 4 + 1] = (f16)w01;
      sWwW[e * 4 + 2] = (f16)w10;
      sWwW[e * 4 + 3] = (f16)w11;
    }
  }

  // ---- Phase B (wave-local): params -> regs, ALL 24 gathers in ONE window ----
  ushort4 po[6];
  f16x4  wv[6];
#pragma unroll
  for (int i = 0; i < 6; ++i) {
    int kh = i >> 1, half = i & 1;
    int e = (half * 8 + pix8) * 3 + kh;           // local pixel index
    po[i] = *(const ushort4*)(sWoW + e * 4);
    wv[i] = *(const f16x4*)(sWwW + e * 4);
  }
  f16x8 gv[24];
#pragma unroll
  for (int i = 0; i < 6; ++i) {
    int b00 = (((int)po[i].x << 8) + (int)po[i].z) << 6;
    int b01 = (((int)po[i].x << 8) + (int)po[i].w) << 6;
    int b10 = (((int)po[i].y << 8) + (int)po[i].z) << 6;
    int b11 = (((int)po[i].y << 8) + (int)po[i].w) << 6;
    gv[i * 4 + 0] = *(const f16x8*)(xb + b00 + cb8);
    gv[i * 4 + 1] = *(const f16x8*)(xb + b01 + cb8);
    gv[i * 4 + 2] = *(const f16x8*)(xb + b10 + cb8);
    gv[i * 4 + 3] = *(const f16x8*)(xb + b11 + cb8);
  }
#pragma unroll
  for (int i = 0; i < 6; ++i) {
    int kh = i >> 1, half = i & 1;
    f16x8 s = gv[i * 4 + 0] * splat8(wv[i][0]) +
              gv[i * 4 + 1] * splat8(wv[i][1]) +
              gv[i * 4 + 2] * splat8(wv[i][2]) +
              gv[i * 4 + 3] * splat8(wv[i][3]);
    // own pixels: (c0 + half*8 + pix8) in [c0, c0+16) -> own sA quarter
    *(f16x8*)(sA + (c0 + half * 8 + pix8) * 200 + kh * 64 + cb8) = s;
  }

  // B-fragments + bias AFTER the gather/FMA window (shrinks peak live set);
  // global loads overlap the barrier wait.
  const int nrow = c0 + lrow;                   // output channel o
  f16x8 Bf[6];
#pragma unroll
  for (int kt = 0; kt < 6; ++kt)
    Bf[kt] = *(const f16x8*)(wtH + nrow * 192 + kt * 32 + kgrp);
  float bdc = b_dcn[nrow];
  __syncthreads();   // barrier #1: all sA written

  // ---- Phase C: MFMA 64x64 += S(64x192) * W(192x64) ----
  f32x4 acc[4];
#pragma unroll
  for (int mt = 0; mt < 4; ++mt) acc[mt] = (f32x4){0.f, 0.f, 0.f, 0.f};
#pragma unroll
  for (int kt = 0; kt < 6; ++kt) {
#pragma unroll
    for (int mt = 0; mt < 4; ++mt) {
      f16x8 Af = *(const f16x8*)(sA + (mt * 16 + lrow) * 200 + kt * 32 + kgrp);
      acc[mt] = __builtin_amdgcn_mfma_f32_16x16x32_f16(Af, Bf[kt], acc[mt],
                                                       0, 0, 0);
    }
  }
  __syncthreads();   // barrier #2: all sA reads done; region becomes sOut

  // ---- Phase D (wave-local rows): +bias, BN partials, sOut[o][66] ----
  float s1 = 0.f, s2 = 0.f;
#pragma unroll
  for (int mt = 0; mt < 4; ++mt) {
    int prow = mt * 16 + lq * 4;                // pixel of acc[mt][0]
    f32x4 vv;
#pragma unroll
    for (int r = 0; r < 4; ++r) {
      float v = acc[mt][r] + bdc;
      vv[r] = v;
      s1 += v;
      s2 += v * v;
    }
    *(f32x4*)(sOut + nrow * 66 + prow) = vv;    // own row (nrow = c0+lrow)
  }
  s1 += __shfl_xor(s1, 16); s1 += __shfl_xor(s1, 32);
  s2 += __shfl_xor(s2, 16); s2 += __shfl_xor(s2, 32);
  // every lane now holds this wave's 64-px totals for ch = c0+(lane&15);
  // waves own disjoint channel sets -> no block combine needed.
  if (lane < 32) {
    int ch = c0 + (lane & 15);
    int j = (lane < 16) ? ch : (64 + ch);
    float v = (lane < 16) ? s1 : s2;
    atomicAdd(&part32[((blockIdx.x & 31) << 7) + j], v);  // fire-and-forget
  }

  // ---- Phase E (wave-local rows, no barrier): pre-BN fp16 store ----
  f16* ob = out16 + (((size_t)b) << 6) * HW + (size_t)h * 256 + w0;
#pragma unroll
  for (int i = 0; i < 16; ++i) {
    int o = c0 + i;                             // own rows only
    ob[(size_t)o * HW + lane] = (f16)sOut[o * 66 + lane];
  }
}

// out = relu((out16-mean)*rsqrt(var+eps)*gamma + beta)  (fp16 in, fp32 out)
// Preamble folds the 32 BN partials per channel (wave-uniform -> s_loads).
__global__ __launch_bounds__(256) void bn_apply(
    const f16* __restrict__ out16, float* __restrict__ out,
    const float* __restrict__ part32, const float* __restrict__ gamma,
    const float* __restrict__ beta) {
  int blk = blockIdx.x;            // 2048 = 512 planes x 4 quarters
  int pl = blk >> 2, q = blk & 3;
  int o = pl & 63;
  float s1 = 0.f, s2 = 0.f;
#pragma unroll
  for (int s = 0; s < 32; ++s) {
    s1 += part32[(s << 7) + o];
    s2 += part32[(s << 7) + 64 + o];
  }
  float mean = s1 * (1.f / (float)NPER);
  float var = s2 * (1.f / (float)NPER) - mean * mean;
  float inv = rsqrtf(var + 1e-5f);
  float sc = gamma[o] * inv;
  float sh = beta[o] - mean * sc;
  const f16x8* src = (const f16x8*)(out16 + (size_t)pl * HW + q * 16384);
  f32x4* dst = (f32x4*)(out + (size_t)pl * HW + q * 16384);
  for (int i = threadIdx.x; i < 2048; i += 256) {
    f16x8 v = src[i];
    f32x4 lo, hi;
    lo[0] = fmaxf(fmaf((float)v[0], sc, sh), 0.f);
    lo[1] = fmaxf(fmaf((float)v[1], sc, sh), 0.f);
    lo[2] = fmaxf(fmaf((float)v[2], sc, sh), 0.f);
    lo[3] = fmaxf(fmaf((float)v[3], sc, sh), 0.f);
    hi[0] = fmaxf(fmaf((float)v[4], sc, sh), 0.f);
    hi[1] = fmaxf(fmaf((float)v[5], sc, sh), 0.f);
    hi[2] = fmaxf(fmaf((float)v[6], sc, sh), 0.f);
    hi[3] = fmaxf(fmaf((float)v[7], sc, sh), 0.f);
    dst[2 * i] = lo;
    dst[2 * i + 1] = hi;
  }
}

extern "C" void kernel_launch(void* const* d_in, const int* in_sizes, int n_in,
                              void* d_out, int out_size, void* d_ws, size_t ws_size,
                              hipStream_t stream) {
  const float* x     = (const float*)d_in[0];
  const float* w_off = (const float*)d_in[1];
  const float* b_off = (const float*)d_in[2];
  const float* w_dcn = (const float*)d_in[3];
  const float* b_dcn = (const float*)d_in[4];
  const float* gamma = (const float*)d_in[5];
  const float* beta  = (const float*)d_in[6];
  float* out = (float*)d_out;
  float* ws  = (float*)d_ws;

  float* part32 = ws + PART32_OFF;
  f16*   wtO  = (f16*)(ws + WTO_OFF);
  f16*   wtH  = (f16*)(ws + WTH_OFF);
  f16*   xT   = (f16*)(ws + XT_OFF);
  f16*   o16  = (f16*)(ws + OUT16_OFF);

  prep_wts<<<48, 256, 0, stream>>>(w_off, w_dcn, wtO, wtH, part32);
  xpose<<<8192, 256, 0, stream>>>(x, xT);
  dcn_fused<<<NBLK, 256, 0, stream>>>(xT, wtO, b_off, wtH, b_dcn, o16, part32);
  bn_apply<<<2048, 256, 0, stream>>>(o16, out, part32, gamma, beta);
}